// Round 1
// baseline (269.951 us; speedup 1.0000x reference)
//
#include <hip/hip_runtime.h>
#include <math.h>

#define EPS 1e-5f
#define NBATCH 8
#define NPTS 2048
#define KNB 16

// ---- workspace layout (in floats) ----
#define WS_PRE 0                           // 8*2048*24 floats
#define WS_IDX (NBATCH*NPTS*24)            // 8*2048*16 ints
#define WS_FWP (WS_IDX + NBATCH*NPTS*16)   // 72
#define WS_FBP (WS_FWP + 72)               // 24
#define WS_FW1 (WS_FBP + 24)               // 576
#define WS_FB1 (WS_FW1 + 576)              // 12
#define WS_FW2 (WS_FB1 + 12)               // 720
#define WS_FB2 (WS_FW2 + 720)              // 12
// total = 656776 floats = ~2.63 MB

// Fold BN affine into conv weights.
__global__ void setup_fold(
    const float* __restrict__ w_pre, const float* __restrict__ b_pre,
    const float* __restrict__ g_pre, const float* __restrict__ be_pre,
    const float* __restrict__ m_pre, const float* __restrict__ v_pre,
    const float* __restrict__ w1, const float* __restrict__ g1,
    const float* __restrict__ be1, const float* __restrict__ m1,
    const float* __restrict__ v1,
    const float* __restrict__ w2, const float* __restrict__ g2,
    const float* __restrict__ be2, const float* __restrict__ m2,
    const float* __restrict__ v2,
    float* __restrict__ ws) {
  int t = threadIdx.x;  // block of 1024
  float* fwp = ws + WS_FWP; float* fbp = ws + WS_FBP;
  float* fw1 = ws + WS_FW1; float* fb1 = ws + WS_FB1;
  float* fw2 = ws + WS_FW2; float* fb2 = ws + WS_FB2;
  if (t < 72)  { int o = t / 3;  fwp[t] = w_pre[t] * (g_pre[o] / sqrtf(v_pre[o] + EPS)); }
  if (t < 24)  { float inv = g_pre[t] / sqrtf(v_pre[t] + EPS);
                 fbp[t] = (b_pre[t] - m_pre[t]) * inv + be_pre[t]; }
  if (t < 576) { int o = t / 48; fw1[t] = w1[t] * (g1[o] / sqrtf(v1[o] + EPS)); }
  if (t >= 576 && t < 588) { int o = t - 576; float inv = g1[o] / sqrtf(v1[o] + EPS);
                 fb1[o] = be1[o] - m1[o] * inv; }
  if (t < 720) { int o = t / 60; fw2[t] = w2[t] * (g2[o] / sqrtf(v2[o] + EPS)); }
  if (t >= 720 && t < 732) { int o = t - 720; float inv = g2[o] / sqrtf(v2[o] + EPS);
                 fb2[o] = be2[o] - m2[o] * inv; }
}

// pre[b][n][o] = relu(fwp[o]·x[b][:][n] + fbp[o]), o<24. One thread per point.
__global__ __launch_bounds__(256) void pre_kernel(
    const float* __restrict__ x, const float* __restrict__ ws,
    float* __restrict__ pre) {
  const float* fwp = ws + WS_FWP;
  const float* fbp = ws + WS_FBP;
  int p = blockIdx.x * 256 + threadIdx.x;   // 0..16383
  int b = p >> 11, n = p & (NPTS - 1);
  const float* xb = x + (size_t)b * 3 * NPTS;
  float x0 = xb[n], x1 = xb[NPTS + n], x2 = xb[2 * NPTS + n];
  float* o = pre + (size_t)p * 24;
  float vals[24];
#pragma unroll
  for (int c = 0; c < 24; ++c) {
    float v = fmaf(fwp[c * 3 + 0], x0,
              fmaf(fwp[c * 3 + 1], x1,
              fmaf(fwp[c * 3 + 2], x2, fbp[c])));
    vals[c] = fmaxf(v, 0.f);
  }
  float4* o4 = (float4*)o;
#pragma unroll
  for (int i = 0; i < 6; ++i)
    o4[i] = make_float4(vals[4*i], vals[4*i+1], vals[4*i+2], vals[4*i+3]);
}

// Exact 16-NN. Block = 512 threads = 64 points x 8 candidate slices.
// Replicates reference fp32 distance arithmetic (no FMA contraction).
__global__ __launch_bounds__(512) void knn_kernel(
    const float* __restrict__ x, int* __restrict__ knn_out) {
  extern __shared__ char smem[];
  float* sx  = (float*)smem;           // [2048]
  float* sy  = sx + NPTS;
  float* sz  = sy + NPTS;
  float* ssq = sz + NPTS;              // 32 KB total
  int b = blockIdx.x >> 5;             // 8 batches
  int chunk = blockIdx.x & 31;         // 32 chunks of 64 points
  int tid = threadIdx.x;
  const float* xb = x + (size_t)b * 3 * NPTS;
  for (int j = tid; j < NPTS; j += 512) {
    float xx = xb[j], yy = xb[NPTS + j], zz = xb[2 * NPTS + j];
    sx[j] = xx; sy[j] = yy; sz[j] = zz;
    ssq[j] = __fadd_rn(__fadd_rn(__fmul_rn(xx, xx), __fmul_rn(yy, yy)),
                       __fmul_rn(zz, zz));
  }
  __syncthreads();
  int s = tid >> 6;                    // slice 0..7 (wave-uniform)
  int p = tid & 63;                    // point within chunk
  int n = chunk * 64 + p;
  float xn = sx[n], yn = sy[n], zn = sz[n], sqn = ssq[n];
  float bd[16]; int bi[16];
#pragma unroll
  for (int t = 0; t < 16; ++t) { bd[t] = 3.4e38f; bi[t] = 0; }
  int j0 = s * 256;
#pragma unroll 1
  for (int jj = 0; jj < 256; ++jj) {
    int j = j0 + jj;
    float dot = __fadd_rn(__fadd_rn(__fmul_rn(xn, sx[j]), __fmul_rn(yn, sy[j])),
                          __fmul_rn(zn, sz[j]));
    float d2 = __fsub_rn(__fadd_rn(sqn, ssq[j]), __fmul_rn(2.0f, dot));
    if (j != n && d2 < bd[15]) {
      float dc = d2; int ic = j;
#pragma unroll
      for (int t = 0; t < 16; ++t) {
        bool c = dc < bd[t];
        float od = bd[t]; int oi = bi[t];
        bd[t] = c ? dc : bd[t]; bi[t] = c ? ic : bi[t];
        dc = c ? od : dc;       ic = c ? oi : ic;
      }
    }
  }
  __syncthreads();   // coords now dead; reuse LDS for partials
  float* pd = (float*)smem;                                   // [8][64][16] f32 = 32KB
  unsigned short* pix = (unsigned short*)(smem + 8*64*16*4);  // [8][64][16] u16 = 16KB
#pragma unroll
  for (int t = 0; t < 16; ++t) {
    pd[(s * 64 + p) * 16 + t] = bd[t];
    pix[(s * 64 + p) * 16 + t] = (unsigned short)bi[t];
  }
  __syncthreads();
  if (tid < 64) {
    float md[16]; int mi[16];
#pragma unroll
    for (int t = 0; t < 16; ++t) { md[t] = 3.4e38f; mi[t] = 0; }
    for (int ss = 0; ss < 8; ++ss) {
      for (int t = 0; t < 16; ++t) {
        float dc = pd[(ss * 64 + tid) * 16 + t];
        if (dc >= md[15]) break;   // slice lists are sorted ascending
        int ic = (int)pix[(ss * 64 + tid) * 16 + t];
#pragma unroll
        for (int u = 0; u < 16; ++u) {
          bool c = dc < md[u];
          float od = md[u]; int oi = mi[u];
          md[u] = c ? dc : md[u]; mi[u] = c ? ic : mi[u];
          dc = c ? od : dc;       ic = c ? oi : ic;
        }
      }
    }
    int nn2 = chunk * 64 + tid;
    int* o = knn_out + ((size_t)b * NPTS + nn2) * KNB;
#pragma unroll
    for (int t = 0; t < 16; ++t) o[t] = mi[t];
  }
}

// Fused edge-MLP + max over neighbors. 16 lanes per point (one per neighbor).
__global__ __launch_bounds__(256) void mlp_kernel(
    const float* __restrict__ pre, const int* __restrict__ knn,
    const float* __restrict__ x, const float* __restrict__ ws,
    const float* __restrict__ w3, float* __restrict__ out) {
  const float* fw1 = ws + WS_FW1; const float* fb1 = ws + WS_FB1;
  const float* fw2 = ws + WS_FW2; const float* fb2 = ws + WS_FB2;
  int tid = threadIdx.x;
  int k  = tid & 15;
  int pl = tid >> 4;                       // 0..15
  int p = blockIdx.x * 16 + pl;            // 0..16383
  int b = p >> 11, n = p & (NPTS - 1);
  const float* cptr = pre + (size_t)p * 24;
  int nb = knn[(size_t)p * KNB + k];
  const float* nptr = pre + ((size_t)(b << 11) + nb) * 24;
  float cen[24], nbf[24];
  const float4* c4 = (const float4*)cptr;
  const float4* n4 = (const float4*)nptr;
#pragma unroll
  for (int i = 0; i < 6; ++i) {
    float4 a = c4[i];
    cen[4*i] = a.x; cen[4*i+1] = a.y; cen[4*i+2] = a.z; cen[4*i+3] = a.w;
    float4 q = n4[i];
    nbf[4*i] = q.x; nbf[4*i+1] = q.y; nbf[4*i+2] = q.z; nbf[4*i+3] = q.w;
  }
  // h1 = relu(fw1 @ [cen, nbf] + fb1)
  float h1[12];
#pragma unroll
  for (int o = 0; o < 12; ++o) {
    float a = fb1[o];
#pragma unroll
    for (int i = 0; i < 24; ++i) a = fmaf(fw1[o*48 + i],      cen[i], a);
#pragma unroll
    for (int i = 0; i < 24; ++i) a = fmaf(fw1[o*48 + 24 + i], nbf[i], a);
    h1[o] = fmaxf(a, 0.f);
  }
  // h2 = relu(fw2 @ [h1, cen, nbf] + fb2)
  float h2[12];
#pragma unroll
  for (int o = 0; o < 12; ++o) {
    float a = fb2[o];
#pragma unroll
    for (int i = 0; i < 12; ++i) a = fmaf(fw2[o*60 + i],      h1[i],  a);
#pragma unroll
    for (int i = 0; i < 24; ++i) a = fmaf(fw2[o*60 + 12 + i], cen[i], a);
#pragma unroll
    for (int i = 0; i < 24; ++i) a = fmaf(fw2[o*60 + 36 + i], nbf[i], a);
    h2[o] = fmaxf(a, 0.f);
  }
  // h3 = w3 @ [h2, h1, cen, nbf]   (no BN, no bias)
  float h3[12];
#pragma unroll
  for (int o = 0; o < 12; ++o) {
    float a = 0.f;
#pragma unroll
    for (int i = 0; i < 12; ++i) a = fmaf(w3[o*72 + i],      h2[i],  a);
#pragma unroll
    for (int i = 0; i < 12; ++i) a = fmaf(w3[o*72 + 12 + i], h1[i],  a);
#pragma unroll
    for (int i = 0; i < 24; ++i) a = fmaf(w3[o*72 + 24 + i], cen[i], a);
#pragma unroll
    for (int i = 0; i < 24; ++i) a = fmaf(w3[o*72 + 48 + i], nbf[i], a);
    h3[o] = a;
  }
  // max over the 16 neighbor lanes (cen is k-invariant; skip it)
#pragma unroll
  for (int m = 1; m < 16; m <<= 1) {
#pragma unroll
    for (int o = 0; o < 12; ++o) {
      h1[o] = fmaxf(h1[o], __shfl_xor(h1[o], m, 16));
      h2[o] = fmaxf(h2[o], __shfl_xor(h2[o], m, 16));
      h3[o] = fmaxf(h3[o], __shfl_xor(h3[o], m, 16));
    }
#pragma unroll
    for (int i = 0; i < 24; ++i)
      nbf[i] = fmaxf(nbf[i], __shfl_xor(nbf[i], m, 16));
  }
  if (k == 0) {
    // out[b][c][n]: c: 0-11 h3, 12-23 h2, 24-35 h1, 36-59 cen, 60-83 nbf, 84-86 x
    float* ob = out + (size_t)b * 87 * NPTS + n;
#pragma unroll
    for (int o = 0; o < 12; ++o) {
      ob[(size_t)(0  + o) * NPTS] = h3[o];
      ob[(size_t)(12 + o) * NPTS] = h2[o];
      ob[(size_t)(24 + o) * NPTS] = h1[o];
    }
#pragma unroll
    for (int i = 0; i < 24; ++i) {
      ob[(size_t)(36 + i) * NPTS] = cen[i];
      ob[(size_t)(60 + i) * NPTS] = nbf[i];
    }
    const float* xb = x + (size_t)b * 3 * NPTS + n;
    ob[(size_t)84 * NPTS] = xb[0];
    ob[(size_t)85 * NPTS] = xb[NPTS];
    ob[(size_t)86 * NPTS] = xb[2 * NPTS];
  }
}

extern "C" void kernel_launch(void* const* d_in, const int* in_sizes, int n_in,
                              void* d_out, int out_size, void* d_ws, size_t ws_size,
                              hipStream_t stream) {
  (void)in_sizes; (void)n_in; (void)out_size; (void)ws_size;
  const float* x     = (const float*)d_in[0];
  const float* w_pre = (const float*)d_in[1];
  const float* b_pre = (const float*)d_in[2];
  const float* g_pre = (const float*)d_in[3];
  const float* be_pre= (const float*)d_in[4];
  const float* m_pre = (const float*)d_in[5];
  const float* v_pre = (const float*)d_in[6];
  const float* w1    = (const float*)d_in[7];
  const float* g1    = (const float*)d_in[8];
  const float* be1   = (const float*)d_in[9];
  const float* m1    = (const float*)d_in[10];
  const float* v1    = (const float*)d_in[11];
  const float* w2    = (const float*)d_in[12];
  const float* g2    = (const float*)d_in[13];
  const float* be2   = (const float*)d_in[14];
  const float* m2    = (const float*)d_in[15];
  const float* v2    = (const float*)d_in[16];
  const float* w3    = (const float*)d_in[17];
  float* ws  = (float*)d_ws;
  float* pre = ws + WS_PRE;
  int*   knn = (int*)(ws + WS_IDX);
  float* out = (float*)d_out;

  setup_fold<<<1, 1024, 0, stream>>>(w_pre, b_pre, g_pre, be_pre, m_pre, v_pre,
                                     w1, g1, be1, m1, v1,
                                     w2, g2, be2, m2, v2, ws);
  pre_kernel<<<64, 256, 0, stream>>>(x, ws, pre);
  knn_kernel<<<NBATCH * 32, 512, 49152, stream>>>(x, knn);
  mlp_kernel<<<NBATCH * NPTS / 16, 256, 0, stream>>>(pre, knn, x, ws, w3, out);
}

// Round 2
// 250.141 us; speedup vs baseline: 1.0792x; 1.0792x over previous
//
#include <hip/hip_runtime.h>
#include <math.h>

#define EPS 1e-5f
#define NBATCH 8
#define NPTS 2048
#define KNB 16
#define BIG 3.2e38f

// ---- workspace layout (in floats) ----
#define WS_PRE 0                            // 16384*24
#define WS_AUX (16384*24)                   // 16384*72
#define WS_IDX (WS_AUX + 16384*72)          // 16384*16 ints
#define WS_FWP (WS_IDX + 16384*16)          // 72
#define WS_FBP (WS_FWP + 72)                // 24
#define WS_FW1 (WS_FBP + 24)                // 576
#define WS_FB1 (WS_FW1 + 576)               // 12
#define WS_FW2 (WS_FB1 + 12)                // 720
#define WS_FB2 (WS_FW2 + 720)               // 12
// total ~1.84M floats = 7.35 MB

// Fold BN affine into conv weights.
__global__ void setup_fold(
    const float* __restrict__ w_pre, const float* __restrict__ b_pre,
    const float* __restrict__ g_pre, const float* __restrict__ be_pre,
    const float* __restrict__ m_pre, const float* __restrict__ v_pre,
    const float* __restrict__ w1, const float* __restrict__ g1,
    const float* __restrict__ be1, const float* __restrict__ m1,
    const float* __restrict__ v1,
    const float* __restrict__ w2, const float* __restrict__ g2,
    const float* __restrict__ be2, const float* __restrict__ m2,
    const float* __restrict__ v2,
    float* __restrict__ ws) {
  int t = threadIdx.x;  // block of 1024
  float* fwp = ws + WS_FWP; float* fbp = ws + WS_FBP;
  float* fw1 = ws + WS_FW1; float* fb1 = ws + WS_FB1;
  float* fw2 = ws + WS_FW2; float* fb2 = ws + WS_FB2;
  if (t < 72)  { int o = t / 3;  fwp[t] = w_pre[t] * (g_pre[o] / sqrtf(v_pre[o] + EPS)); }
  if (t < 24)  { float inv = g_pre[t] / sqrtf(v_pre[t] + EPS);
                 fbp[t] = (b_pre[t] - m_pre[t]) * inv + be_pre[t]; }
  if (t < 576) { int o = t / 48; fw1[t] = w1[t] * (g1[o] / sqrtf(v1[o] + EPS)); }
  if (t >= 576 && t < 588) { int o = t - 576; float inv = g1[o] / sqrtf(v1[o] + EPS);
                 fb1[o] = be1[o] - m1[o] * inv; }
  if (t < 720) { int o = t / 60; fw2[t] = w2[t] * (g2[o] / sqrtf(v2[o] + EPS)); }
  if (t >= 720 && t < 732) { int o = t - 720; float inv = g2[o] / sqrtf(v2[o] + EPS);
                 fb2[o] = be2[o] - m2[o] * inv; }
}

// Per point: pre[24] = relu(conv+BN), plus per-point MLP partials:
// aux = [ucen1(12) | ucen2(12) | ucen3(12) | a1(12) | a2(12) | a3(12)]
__global__ __launch_bounds__(256) void pre2_kernel(
    const float* __restrict__ x, const float* __restrict__ ws,
    const float* __restrict__ w3,
    float* __restrict__ pre, float* __restrict__ aux) {
  const float* fwp = ws + WS_FWP; const float* fbp = ws + WS_FBP;
  const float* fw1 = ws + WS_FW1; const float* fb1 = ws + WS_FB1;
  const float* fw2 = ws + WS_FW2; const float* fb2 = ws + WS_FB2;
  int p = blockIdx.x * 256 + threadIdx.x;   // 0..16383
  int b = p >> 11, n = p & (NPTS - 1);
  const float* xb = x + (size_t)b * 3 * NPTS;
  float x0 = xb[n], x1 = xb[NPTS + n], x2 = xb[2 * NPTS + n];
  float pr[24];
#pragma unroll
  for (int c = 0; c < 24; ++c) {
    float v = fmaf(fwp[c * 3 + 0], x0,
              fmaf(fwp[c * 3 + 1], x1,
              fmaf(fwp[c * 3 + 2], x2, fbp[c])));
    pr[c] = fmaxf(v, 0.f);
  }
  float4* o4 = (float4*)(pre + (size_t)p * 24);
#pragma unroll
  for (int i = 0; i < 6; ++i)
    o4[i] = make_float4(pr[4*i], pr[4*i+1], pr[4*i+2], pr[4*i+3]);
  float* A = aux + (size_t)p * 72;
#pragma unroll
  for (int o = 0; o < 12; ++o) {
    float u1 = fb1[o], a1 = 0.f, u2 = fb2[o], a2 = 0.f, u3 = 0.f, a3 = 0.f;
#pragma unroll
    for (int i = 0; i < 24; ++i) {
      u1 = fmaf(fw1[o*48 + i],      pr[i], u1);
      a1 = fmaf(fw1[o*48 + 24 + i], pr[i], a1);
      u2 = fmaf(fw2[o*60 + 12 + i], pr[i], u2);
      a2 = fmaf(fw2[o*60 + 36 + i], pr[i], a2);
      u3 = fmaf(w3[o*72 + 24 + i],  pr[i], u3);
      a3 = fmaf(w3[o*72 + 48 + i],  pr[i], a3);
    }
    A[o] = u1; A[12+o] = u2; A[24+o] = u3;
    A[36+o] = a1; A[48+o] = a2; A[60+o] = a3;
  }
}

// Exact 16-NN, 3-phase: branchless value-only top-16, merge for tau, rescan
// for indices. Block = 256 thr = 32 points x 8 slices of 256 candidates.
#define KNN_LDS 54528
__global__ __launch_bounds__(256) void knn_kernel(
    const float* __restrict__ x, int* __restrict__ knn_out) {
  extern __shared__ char smem[];
  float4* C4   = (float4*)smem;              // [2048] coords+sq, 32 KB
  float* slist = (float*)(smem + 32768);     // [128][32] transposed lists, 16 KB
  float* sd2   = (float*)(smem + 49152);     // [32][20]
  int*   sidx  = (int*)(smem + 51712);       // [32][20]
  int*   scnt  = (int*)(smem + 54272);       // [32]
  float* stau  = (float*)(smem + 54400);     // [32]
  int tid = threadIdx.x;
  int b = blockIdx.x >> 6, chunk = blockIdx.x & 63;
  const float* xb = x + (size_t)b * 3 * NPTS;
  for (int j = tid; j < NPTS; j += 256) {
    float xx = xb[j], yy = xb[NPTS + j], zz = xb[2 * NPTS + j];
    float sq = __fadd_rn(__fadd_rn(__fmul_rn(xx, xx), __fmul_rn(yy, yy)),
                         __fmul_rn(zz, zz));
    C4[j] = make_float4(xx, yy, zz, sq);
  }
  for (int j = tid; j < 32 * 20; j += 256) sidx[j] = 0;
  if (tid < 32) scnt[tid] = 0;
  __syncthreads();
  int p = tid & 31, s = tid >> 5;
  int n = chunk * 32 + p;
  float4 me = C4[n];
  const float4* Cs = C4 + s * 256;
  // Phase 1: 4 independent substreams, branchless min/max sorted-16 (values)
  float L[4][16];
#pragma unroll
  for (int u = 0; u < 4; ++u)
#pragma unroll
    for (int t = 0; t < 16; ++t) L[u][t] = BIG;
#pragma unroll 1
  for (int c = 0; c < 256; c += 4) {
#pragma unroll
    for (int u = 0; u < 4; ++u) {
      float4 q = Cs[c + u];
      float dot = __fadd_rn(__fadd_rn(__fmul_rn(me.x, q.x), __fmul_rn(me.y, q.y)),
                            __fmul_rn(me.z, q.z));
      float d2 = __fsub_rn(__fadd_rn(me.w, q.w), __fmul_rn(2.0f, dot));
      d2 = (s * 256 + c + u == n) ? BIG : d2;   // exclude self
#pragma unroll
      for (int t = 15; t >= 1; --t) L[u][t] = fminf(fmaxf(L[u][t-1], d2), L[u][t]);
      L[u][0] = fminf(L[u][0], d2);
    }
  }
  // in-lane merge 4 sorted-16 -> set of 16 (bitonic elementwise-min merges)
  float m01[16], m23[16];
#pragma unroll
  for (int i = 0; i < 16; ++i) m01[i] = fminf(L[0][i], L[1][15 - i]);
#pragma unroll
  for (int i = 0; i < 16; ++i) m23[i] = fminf(L[2][i], L[3][15 - i]);
#pragma unroll
  for (int d = 8; d >= 1; d >>= 1) {
#pragma unroll
    for (int i = 0; i < 16; ++i) {
      if (!(i & d)) {
        float a0 = m01[i], b0 = m01[i | d];
        m01[i] = fminf(a0, b0); m01[i | d] = fmaxf(a0, b0);
        float a1 = m23[i], b1 = m23[i | d];
        m23[i] = fminf(a1, b1); m23[i | d] = fmaxf(a1, b1);
      }
    }
  }
#pragma unroll
  for (int i = 0; i < 16; ++i)
    slist[(s * 16 + i) * 32 + p] = fminf(m01[i], m23[15 - i]);
  __syncthreads();
  // Phase 2: merge 8 slice lists -> exact tau (16th smallest, self excluded)
  if (tid < 32) {
    float M[16];
#pragma unroll
    for (int t = 0; t < 16; ++t) M[t] = BIG;
#pragma unroll 1
    for (int v = 0; v < 128; ++v) {
      float d2 = slist[v * 32 + tid];
#pragma unroll
      for (int t = 15; t >= 1; --t) M[t] = fminf(fmaxf(M[t-1], d2), M[t]);
      M[0] = fminf(M[0], d2);
    }
    stau[tid] = M[15];
  }
  __syncthreads();
  // Phase 3: rescan, collect indices with d2 <= tau
  float tau = stau[p];
#pragma unroll 4
  for (int c = 0; c < 256; ++c) {
    float4 q = Cs[c];
    float dot = __fadd_rn(__fadd_rn(__fmul_rn(me.x, q.x), __fmul_rn(me.y, q.y)),
                          __fmul_rn(me.z, q.z));
    float d2 = __fsub_rn(__fadd_rn(me.w, q.w), __fmul_rn(2.0f, dot));
    int j = s * 256 + c;
    if (d2 <= tau && j != n) {
      int pos = atomicAdd(&scnt[p], 1);
      if (pos < 20) { sd2[p * 20 + pos] = d2; sidx[p * 20 + pos] = j; }
    }
  }
  __syncthreads();
  // Phase 4: rare tie fixup — keep 16 smallest by (d2, idx) lexicographic
  if (tid < 32) {
    int c = scnt[tid]; if (c > 20) c = 20;
    if (c > 16) {
      for (int t = 0; t < 16; ++t) {
        int best = t;
        for (int u = t + 1; u < c; ++u) {
          float da = sd2[tid * 20 + u], db = sd2[tid * 20 + best];
          int ia = sidx[tid * 20 + u], ib = sidx[tid * 20 + best];
          if (da < db || (da == db && ia < ib)) best = u;
        }
        float td = sd2[tid * 20 + t]; sd2[tid * 20 + t] = sd2[tid * 20 + best]; sd2[tid * 20 + best] = td;
        int ti = sidx[tid * 20 + t]; sidx[tid * 20 + t] = sidx[tid * 20 + best]; sidx[tid * 20 + best] = ti;
      }
    }
  }
  __syncthreads();
  for (int t2 = tid; t2 < 512; t2 += 256) {
    int pp = t2 >> 4, kk = t2 & 15;
    knn_out[((size_t)b * NPTS + chunk * 32 + pp) * KNB + kk] = sidx[pp * 20 + kk];
  }
}

// Fused edge-MLP + max. 16 lanes/point; per-sample work reduced to the
// neighbor-dependent 12x12 blocks (W2h, W3h1, W3h2) — weights in LDS.
__global__ __launch_bounds__(256) void mlp_kernel(
    const float* __restrict__ pre, const float* __restrict__ aux,
    const int* __restrict__ knn, const float* __restrict__ x,
    const float* __restrict__ ws, const float* __restrict__ w3,
    float* __restrict__ out) {
  __shared__ float sW2h[144], sW3h2[144], sW3h1[144];
  __shared__ float sout[87 * 16];
  const float* fw2 = ws + WS_FW2;
  int tid = threadIdx.x;
  if (tid < 144) {
    int o = tid / 12, i = tid - o * 12;
    sW2h[tid]  = fw2[o * 60 + i];
    sW3h2[tid] = w3[o * 72 + i];
    sW3h1[tid] = w3[o * 72 + 12 + i];
  }
  __syncthreads();
  int k = tid & 15, pl = tid >> 4;
  int p = blockIdx.x * 16 + pl;            // 0..16383
  int b = p >> 11, n = p & (NPTS - 1);
  int nb = knn[(size_t)p * KNB + k];
  const float4* u4 = (const float4*)(aux + (size_t)p * 72);
  const float4* a4 = (const float4*)(aux + ((size_t)(b << 11) + nb) * 72 + 36);
  float uc[36], av[36];
#pragma unroll
  for (int i = 0; i < 9; ++i) {
    float4 t = u4[i];
    uc[4*i] = t.x; uc[4*i+1] = t.y; uc[4*i+2] = t.z; uc[4*i+3] = t.w;
    float4 t2 = a4[i];
    av[4*i] = t2.x; av[4*i+1] = t2.y; av[4*i+2] = t2.z; av[4*i+3] = t2.w;
  }
  float h1[12], h2[12], h3[12];
#pragma unroll
  for (int o = 0; o < 12; ++o) h1[o] = fmaxf(uc[o] + av[o], 0.f);
#pragma unroll
  for (int o = 0; o < 12; ++o) {
    float a = uc[12 + o] + av[12 + o];
#pragma unroll
    for (int i = 0; i < 12; ++i) a = fmaf(sW2h[o * 12 + i], h1[i], a);
    h2[o] = fmaxf(a, 0.f);
  }
#pragma unroll
  for (int o = 0; o < 12; ++o) {
    float a = uc[24 + o] + av[24 + o];
#pragma unroll
    for (int i = 0; i < 12; ++i) a = fmaf(sW3h2[o * 12 + i], h2[i], a);
#pragma unroll
    for (int i = 0; i < 12; ++i) a = fmaf(sW3h1[o * 12 + i], h1[i], a);
    h3[o] = a;
  }
  float nbf[24];
  const float4* pn4 = (const float4*)(pre + ((size_t)(b << 11) + nb) * 24);
#pragma unroll
  for (int i = 0; i < 6; ++i) {
    float4 t = pn4[i];
    nbf[4*i] = t.x; nbf[4*i+1] = t.y; nbf[4*i+2] = t.z; nbf[4*i+3] = t.w;
  }
#pragma unroll
  for (int m = 1; m < 16; m <<= 1) {
#pragma unroll
    for (int o = 0; o < 12; ++o) {
      h1[o] = fmaxf(h1[o], __shfl_xor(h1[o], m, 16));
      h2[o] = fmaxf(h2[o], __shfl_xor(h2[o], m, 16));
      h3[o] = fmaxf(h3[o], __shfl_xor(h3[o], m, 16));
    }
#pragma unroll
    for (int i = 0; i < 24; ++i)
      nbf[i] = fmaxf(nbf[i], __shfl_xor(nbf[i], m, 16));
  }
  if (k == 0) {
    const float4* c4 = (const float4*)(pre + (size_t)p * 24);
#pragma unroll
    for (int o = 0; o < 12; ++o) {
      sout[(0  + o) * 16 + pl] = h3[o];
      sout[(12 + o) * 16 + pl] = h2[o];
      sout[(24 + o) * 16 + pl] = h1[o];
    }
#pragma unroll
    for (int i = 0; i < 6; ++i) {
      float4 t = c4[i];
      sout[(36 + 4*i    ) * 16 + pl] = t.x;
      sout[(36 + 4*i + 1) * 16 + pl] = t.y;
      sout[(36 + 4*i + 2) * 16 + pl] = t.z;
      sout[(36 + 4*i + 3) * 16 + pl] = t.w;
    }
#pragma unroll
    for (int i = 0; i < 24; ++i) sout[(60 + i) * 16 + pl] = nbf[i];
    const float* xb = x + (size_t)b * 3 * NPTS + n;
    sout[84 * 16 + pl] = xb[0];
    sout[85 * 16 + pl] = xb[NPTS];
    sout[86 * 16 + pl] = xb[2 * NPTS];
  }
  __syncthreads();
  int n0 = (blockIdx.x * 16) & (NPTS - 1);
  float* ob = out + (size_t)b * 87 * NPTS;
  for (int j2 = tid; j2 < 87 * 16; j2 += 256) {
    int c = j2 >> 4, i = j2 & 15;
    ob[(size_t)c * NPTS + n0 + i] = sout[j2];
  }
}

extern "C" void kernel_launch(void* const* d_in, const int* in_sizes, int n_in,
                              void* d_out, int out_size, void* d_ws, size_t ws_size,
                              hipStream_t stream) {
  (void)in_sizes; (void)n_in; (void)out_size; (void)ws_size;
  const float* x     = (const float*)d_in[0];
  const float* w_pre = (const float*)d_in[1];
  const float* b_pre = (const float*)d_in[2];
  const float* g_pre = (const float*)d_in[3];
  const float* be_pre= (const float*)d_in[4];
  const float* m_pre = (const float*)d_in[5];
  const float* v_pre = (const float*)d_in[6];
  const float* w1    = (const float*)d_in[7];
  const float* g1    = (const float*)d_in[8];
  const float* be1   = (const float*)d_in[9];
  const float* m1    = (const float*)d_in[10];
  const float* v1    = (const float*)d_in[11];
  const float* w2    = (const float*)d_in[12];
  const float* g2    = (const float*)d_in[13];
  const float* be2   = (const float*)d_in[14];
  const float* m2    = (const float*)d_in[15];
  const float* v2    = (const float*)d_in[16];
  const float* w3    = (const float*)d_in[17];
  float* ws  = (float*)d_ws;
  float* pre = ws + WS_PRE;
  float* aux = ws + WS_AUX;
  int*   knn = (int*)(ws + WS_IDX);
  float* out = (float*)d_out;

  setup_fold<<<1, 1024, 0, stream>>>(w_pre, b_pre, g_pre, be_pre, m_pre, v_pre,
                                     w1, g1, be1, m1, v1,
                                     w2, g2, be2, m2, v2, ws);
  pre2_kernel<<<64, 256, 0, stream>>>(x, ws, w3, pre, aux);
  knn_kernel<<<NBATCH * 64, 256, KNN_LDS, stream>>>(x, knn);
  mlp_kernel<<<NBATCH * NPTS / 16, 256, 0, stream>>>(pre, aux, knn, x, ws, w3, out);
}

// Round 3
// 202.118 us; speedup vs baseline: 1.3356x; 1.2376x over previous
//
#include <hip/hip_runtime.h>
#include <math.h>

#define EPS 1e-5f
#define NBATCH 8
#define NPTS 2048
#define KNB 16
#define BIG 3.2e38f

// ---- workspace layout (in floats) ----
#define WS_PRE 0                            // 16384*24
#define WS_AUX (16384*24)                   // 16384*72
#define WS_IDX (WS_AUX + 16384*72)          // 16384*16 ints
#define WS_FWP (WS_IDX + 16384*16)          // 72
#define WS_FBP (WS_FWP + 72)                // 24
#define WS_FW1 (WS_FBP + 24)                // 576
#define WS_FB1 (WS_FW1 + 576)               // 12
#define WS_FW2 (WS_FB1 + 12)                // 720
#define WS_FB2 (WS_FW2 + 720)               // 12

// Fold BN affine into conv weights.
__global__ void setup_fold(
    const float* __restrict__ w_pre, const float* __restrict__ b_pre,
    const float* __restrict__ g_pre, const float* __restrict__ be_pre,
    const float* __restrict__ m_pre, const float* __restrict__ v_pre,
    const float* __restrict__ w1, const float* __restrict__ g1,
    const float* __restrict__ be1, const float* __restrict__ m1,
    const float* __restrict__ v1,
    const float* __restrict__ w2, const float* __restrict__ g2,
    const float* __restrict__ be2, const float* __restrict__ m2,
    const float* __restrict__ v2,
    float* __restrict__ ws) {
  int t = threadIdx.x;  // block of 1024
  float* fwp = ws + WS_FWP; float* fbp = ws + WS_FBP;
  float* fw1 = ws + WS_FW1; float* fb1 = ws + WS_FB1;
  float* fw2 = ws + WS_FW2; float* fb2 = ws + WS_FB2;
  if (t < 72)  { int o = t / 3;  fwp[t] = w_pre[t] * (g_pre[o] / sqrtf(v_pre[o] + EPS)); }
  if (t < 24)  { float inv = g_pre[t] / sqrtf(v_pre[t] + EPS);
                 fbp[t] = (b_pre[t] - m_pre[t]) * inv + be_pre[t]; }
  if (t < 576) { int o = t / 48; fw1[t] = w1[t] * (g1[o] / sqrtf(v1[o] + EPS)); }
  if (t >= 576 && t < 588) { int o = t - 576; float inv = g1[o] / sqrtf(v1[o] + EPS);
                 fb1[o] = be1[o] - m1[o] * inv; }
  if (t < 720) { int o = t / 60; fw2[t] = w2[t] * (g2[o] / sqrtf(v2[o] + EPS)); }
  if (t >= 720 && t < 732) { int o = t - 720; float inv = g2[o] / sqrtf(v2[o] + EPS);
                 fb2[o] = be2[o] - m2[o] * inv; }
}

// Per point: pre[24] = relu(conv+BN), plus per-point MLP partials:
// aux = [ucen1(12) | ucen2(12) | ucen3(12) | a1(12) | a2(12) | a3(12)]
__global__ __launch_bounds__(256) void pre2_kernel(
    const float* __restrict__ x, const float* __restrict__ ws,
    const float* __restrict__ w3,
    float* __restrict__ pre, float* __restrict__ aux) {
  const float* fwp = ws + WS_FWP; const float* fbp = ws + WS_FBP;
  const float* fw1 = ws + WS_FW1; const float* fb1 = ws + WS_FB1;
  const float* fw2 = ws + WS_FW2; const float* fb2 = ws + WS_FB2;
  int p = blockIdx.x * 256 + threadIdx.x;   // 0..16383
  int b = p >> 11, n = p & (NPTS - 1);
  const float* xb = x + (size_t)b * 3 * NPTS;
  float x0 = xb[n], x1 = xb[NPTS + n], x2 = xb[2 * NPTS + n];
  float pr[24];
#pragma unroll
  for (int c = 0; c < 24; ++c) {
    float v = fmaf(fwp[c * 3 + 0], x0,
              fmaf(fwp[c * 3 + 1], x1,
              fmaf(fwp[c * 3 + 2], x2, fbp[c])));
    pr[c] = fmaxf(v, 0.f);
  }
  float4* o4 = (float4*)(pre + (size_t)p * 24);
#pragma unroll
  for (int i = 0; i < 6; ++i)
    o4[i] = make_float4(pr[4*i], pr[4*i+1], pr[4*i+2], pr[4*i+3]);
  float* A = aux + (size_t)p * 72;
#pragma unroll
  for (int o = 0; o < 12; ++o) {
    float u1 = fb1[o], a1 = 0.f, u2 = fb2[o], a2 = 0.f, u3 = 0.f, a3 = 0.f;
#pragma unroll
    for (int i = 0; i < 24; ++i) {
      u1 = fmaf(fw1[o*48 + i],      pr[i], u1);
      a1 = fmaf(fw1[o*48 + 24 + i], pr[i], a1);
      u2 = fmaf(fw2[o*60 + 12 + i], pr[i], u2);
      a2 = fmaf(fw2[o*60 + 36 + i], pr[i], a2);
      u3 = fmaf(w3[o*72 + 24 + i],  pr[i], u3);
      a3 = fmaf(w3[o*72 + 48 + i],  pr[i], a3);
    }
    A[o] = u1; A[12+o] = u2; A[24+o] = u3;
    A[36+o] = a1; A[48+o] = a2; A[60+o] = a3;
  }
}

// Exact 16-NN. Block = 256 thr = 16 points x 16 slices of 128 candidates.
// Phase 1: per-lane branchless sorted-16 (values only).
// Phase 2: parallel bitonic merge tree (16->8->4->2->1 lists) -> exact tau.
// Phase 3: rescan, collect d2 <= tau. Phase 4: (d2,idx) tie fixup.
#define KNN_LDS 52352
__global__ __launch_bounds__(256) void knn_kernel(
    const float* __restrict__ x, int* __restrict__ knn_out) {
  extern __shared__ char smem[];
  float4* C4   = (float4*)smem;              // [2048] coords+sq, 32 KB
  float* slist = (float*)(smem + 32768);     // [16 lists][16 vals][16 pts], 16 KB
  float* sd2   = (float*)(smem + 49152);     // [16][24]
  int*   sidx  = (int*)(smem + 50688);       // [16][24]
  int*   scnt  = (int*)(smem + 52224);       // [16]
  int tid = threadIdx.x;
  int b = blockIdx.x >> 7, chunk = blockIdx.x & 127;
  const float* xb = x + (size_t)b * 3 * NPTS;
  for (int j = tid; j < NPTS; j += 256) {
    float xx = xb[j], yy = xb[NPTS + j], zz = xb[2 * NPTS + j];
    float sq = __fadd_rn(__fadd_rn(__fmul_rn(xx, xx), __fmul_rn(yy, yy)),
                         __fmul_rn(zz, zz));
    C4[j] = make_float4(xx, yy, zz, sq);
  }
  for (int j = tid; j < 16 * 24; j += 256) sidx[j] = 0;
  if (tid < 16) scnt[tid] = 0;
  __syncthreads();
  int p = tid & 15, s = tid >> 4;            // point 0..15, slice 0..15
  int n = chunk * 16 + p;
  float4 me = C4[n];
  const float4* Cs = C4 + s * 128;
  int selfc = n - s * 128;                   // in [0,128) only for the self slice
  // Phase 1
  float L[16];
#pragma unroll
  for (int t = 0; t < 16; ++t) L[t] = BIG;
#pragma unroll 4
  for (int c = 0; c < 128; ++c) {
    float4 q = Cs[c];
    float dot = __fadd_rn(__fadd_rn(__fmul_rn(me.x, q.x), __fmul_rn(me.y, q.y)),
                          __fmul_rn(me.z, q.z));
    float d2 = __fsub_rn(__fadd_rn(me.w, q.w), __fmul_rn(2.0f, dot));
    d2 = (c == selfc) ? BIG : d2;
#pragma unroll
    for (int t = 15; t >= 1; --t) L[t] = fminf(fmaxf(L[t-1], d2), L[t]);
    L[0] = fminf(L[0], d2);
  }
#pragma unroll
  for (int i = 0; i < 16; ++i) slist[(s * 16 + i) * 16 + p] = L[i];
  __syncthreads();
  // Phase 2: merge tree. Worker w (=tid>>4) merges lists 2w,2w+1 -> list w.
  for (int W = 8; W >= 1; W >>= 1) {
    int w = tid >> 4;
    bool act = (w < W);
    float a[16], bb[16];
    if (act) {
#pragma unroll
      for (int i = 0; i < 16; ++i) a[i]  = slist[((2 * w) * 16 + i) * 16 + p];
#pragma unroll
      for (int i = 0; i < 16; ++i) bb[i] = slist[((2 * w + 1) * 16 + i) * 16 + p];
    }
    __syncthreads();
    if (act) {
      float m16[16];
#pragma unroll
      for (int i = 0; i < 16; ++i) m16[i] = fminf(a[i], bb[15 - i]);
#pragma unroll
      for (int d = 8; d >= 1; d >>= 1) {
#pragma unroll
        for (int i = 0; i < 16; ++i) {
          if (!(i & d)) {
            float lo = fminf(m16[i], m16[i | d]);
            float hi = fmaxf(m16[i], m16[i | d]);
            m16[i] = lo; m16[i | d] = hi;
          }
        }
      }
#pragma unroll
      for (int i = 0; i < 16; ++i) slist[(w * 16 + i) * 16 + p] = m16[i];
    }
    __syncthreads();
  }
  float tau = slist[15 * 16 + p];            // exact 16th smallest (self excluded)
  // Phase 3: rescan, collect indices with d2 <= tau
#pragma unroll 4
  for (int c = 0; c < 128; ++c) {
    float4 q = Cs[c];
    float dot = __fadd_rn(__fadd_rn(__fmul_rn(me.x, q.x), __fmul_rn(me.y, q.y)),
                          __fmul_rn(me.z, q.z));
    float d2 = __fsub_rn(__fadd_rn(me.w, q.w), __fmul_rn(2.0f, dot));
    int j = s * 128 + c;
    if (d2 <= tau && j != n) {
      int pos = atomicAdd(&scnt[p], 1);
      if (pos < 24) { sd2[p * 24 + pos] = d2; sidx[p * 24 + pos] = j; }
    }
  }
  __syncthreads();
  // Phase 4: rare tie fixup — keep 16 smallest by (d2, idx) lexicographic
  if (tid < 16) {
    int c = scnt[tid]; if (c > 24) c = 24;
    if (c > 16) {
      for (int t = 0; t < 16; ++t) {
        int best = t;
        for (int u = t + 1; u < c; ++u) {
          float da = sd2[tid * 24 + u], db = sd2[tid * 24 + best];
          int ia = sidx[tid * 24 + u], ib = sidx[tid * 24 + best];
          if (da < db || (da == db && ia < ib)) best = u;
        }
        float td = sd2[tid * 24 + t]; sd2[tid * 24 + t] = sd2[tid * 24 + best]; sd2[tid * 24 + best] = td;
        int ti = sidx[tid * 24 + t]; sidx[tid * 24 + t] = sidx[tid * 24 + best]; sidx[tid * 24 + best] = ti;
      }
    }
  }
  __syncthreads();
  {
    int pp = tid >> 4, kk = tid & 15;
    knn_out[((size_t)b * NPTS + chunk * 16 + pp) * KNB + kk] = sidx[pp * 24 + kk];
  }
}

// Fused edge-MLP + max. 16 lanes/point; per-sample work reduced to the
// neighbor-dependent 12x12 blocks (W2h, W3h1, W3h2) — weights in LDS.
__global__ __launch_bounds__(256) void mlp_kernel(
    const float* __restrict__ pre, const float* __restrict__ aux,
    const int* __restrict__ knn, const float* __restrict__ x,
    const float* __restrict__ ws, const float* __restrict__ w3,
    float* __restrict__ out) {
  __shared__ float sW2h[144], sW3h2[144], sW3h1[144];
  __shared__ float sout[87 * 16];
  const float* fw2 = ws + WS_FW2;
  int tid = threadIdx.x;
  if (tid < 144) {
    int o = tid / 12, i = tid - o * 12;
    sW2h[tid]  = fw2[o * 60 + i];
    sW3h2[tid] = w3[o * 72 + i];
    sW3h1[tid] = w3[o * 72 + 12 + i];
  }
  __syncthreads();
  int k = tid & 15, pl = tid >> 4;
  int p = blockIdx.x * 16 + pl;            // 0..16383
  int b = p >> 11, n = p & (NPTS - 1);
  int nb = knn[(size_t)p * KNB + k];
  const float4* u4 = (const float4*)(aux + (size_t)p * 72);
  const float4* a4 = (const float4*)(aux + ((size_t)(b << 11) + nb) * 72 + 36);
  float uc[36], av[36];
#pragma unroll
  for (int i = 0; i < 9; ++i) {
    float4 t = u4[i];
    uc[4*i] = t.x; uc[4*i+1] = t.y; uc[4*i+2] = t.z; uc[4*i+3] = t.w;
    float4 t2 = a4[i];
    av[4*i] = t2.x; av[4*i+1] = t2.y; av[4*i+2] = t2.z; av[4*i+3] = t2.w;
  }
  float h1[12], h2[12], h3[12];
#pragma unroll
  for (int o = 0; o < 12; ++o) h1[o] = fmaxf(uc[o] + av[o], 0.f);
#pragma unroll
  for (int o = 0; o < 12; ++o) {
    float a = uc[12 + o] + av[12 + o];
#pragma unroll
    for (int i = 0; i < 12; ++i) a = fmaf(sW2h[o * 12 + i], h1[i], a);
    h2[o] = fmaxf(a, 0.f);
  }
#pragma unroll
  for (int o = 0; o < 12; ++o) {
    float a = uc[24 + o] + av[24 + o];
#pragma unroll
    for (int i = 0; i < 12; ++i) a = fmaf(sW3h2[o * 12 + i], h2[i], a);
#pragma unroll
    for (int i = 0; i < 12; ++i) a = fmaf(sW3h1[o * 12 + i], h1[i], a);
    h3[o] = a;
  }
  float nbf[24];
  const float4* pn4 = (const float4*)(pre + ((size_t)(b << 11) + nb) * 24);
#pragma unroll
  for (int i = 0; i < 6; ++i) {
    float4 t = pn4[i];
    nbf[4*i] = t.x; nbf[4*i+1] = t.y; nbf[4*i+2] = t.z; nbf[4*i+3] = t.w;
  }
#pragma unroll
  for (int m = 1; m < 16; m <<= 1) {
#pragma unroll
    for (int o = 0; o < 12; ++o) {
      h1[o] = fmaxf(h1[o], __shfl_xor(h1[o], m, 16));
      h2[o] = fmaxf(h2[o], __shfl_xor(h2[o], m, 16));
      h3[o] = fmaxf(h3[o], __shfl_xor(h3[o], m, 16));
    }
#pragma unroll
    for (int i = 0; i < 24; ++i)
      nbf[i] = fmaxf(nbf[i], __shfl_xor(nbf[i], m, 16));
  }
  if (k == 0) {
    const float4* c4 = (const float4*)(pre + (size_t)p * 24);
#pragma unroll
    for (int o = 0; o < 12; ++o) {
      sout[(0  + o) * 16 + pl] = h3[o];
      sout[(12 + o) * 16 + pl] = h2[o];
      sout[(24 + o) * 16 + pl] = h1[o];
    }
#pragma unroll
    for (int i = 0; i < 6; ++i) {
      float4 t = c4[i];
      sout[(36 + 4*i    ) * 16 + pl] = t.x;
      sout[(36 + 4*i + 1) * 16 + pl] = t.y;
      sout[(36 + 4*i + 2) * 16 + pl] = t.z;
      sout[(36 + 4*i + 3) * 16 + pl] = t.w;
    }
#pragma unroll
    for (int i = 0; i < 24; ++i) sout[(60 + i) * 16 + pl] = nbf[i];
    const float* xb = x + (size_t)b * 3 * NPTS + n;
    sout[84 * 16 + pl] = xb[0];
    sout[85 * 16 + pl] = xb[NPTS];
    sout[86 * 16 + pl] = xb[2 * NPTS];
  }
  __syncthreads();
  int n0 = (blockIdx.x * 16) & (NPTS - 1);
  float* ob = out + (size_t)b * 87 * NPTS;
  for (int j2 = tid; j2 < 87 * 16; j2 += 256) {
    int c = j2 >> 4, i = j2 & 15;
    ob[(size_t)c * NPTS + n0 + i] = sout[j2];
  }
}

extern "C" void kernel_launch(void* const* d_in, const int* in_sizes, int n_in,
                              void* d_out, int out_size, void* d_ws, size_t ws_size,
                              hipStream_t stream) {
  (void)in_sizes; (void)n_in; (void)out_size; (void)ws_size;
  const float* x     = (const float*)d_in[0];
  const float* w_pre = (const float*)d_in[1];
  const float* b_pre = (const float*)d_in[2];
  const float* g_pre = (const float*)d_in[3];
  const float* be_pre= (const float*)d_in[4];
  const float* m_pre = (const float*)d_in[5];
  const float* v_pre = (const float*)d_in[6];
  const float* w1    = (const float*)d_in[7];
  const float* g1    = (const float*)d_in[8];
  const float* be1   = (const float*)d_in[9];
  const float* m1    = (const float*)d_in[10];
  const float* v1    = (const float*)d_in[11];
  const float* w2    = (const float*)d_in[12];
  const float* g2    = (const float*)d_in[13];
  const float* be2   = (const float*)d_in[14];
  const float* m2    = (const float*)d_in[15];
  const float* v2    = (const float*)d_in[16];
  const float* w3    = (const float*)d_in[17];
  float* ws  = (float*)d_ws;
  float* pre = ws + WS_PRE;
  float* aux = ws + WS_AUX;
  int*   knn = (int*)(ws + WS_IDX);
  float* out = (float*)d_out;

  setup_fold<<<1, 1024, 0, stream>>>(w_pre, b_pre, g_pre, be_pre, m_pre, v_pre,
                                     w1, g1, be1, m1, v1,
                                     w2, g2, be2, m2, v2, ws);
  pre2_kernel<<<64, 256, 0, stream>>>(x, ws, w3, pre, aux);
  knn_kernel<<<NBATCH * 128, 256, KNN_LDS, stream>>>(x, knn);
  mlp_kernel<<<NBATCH * NPTS / 16, 256, 0, stream>>>(pre, aux, knn, x, ws, w3, out);
}

// Round 4
// 176.712 us; speedup vs baseline: 1.5276x; 1.1438x over previous
//
#include <hip/hip_runtime.h>
#include <math.h>

#define EPS 1e-5f
#define NBATCH 8
#define NPTS 2048
#define KNB 16
#define BIG 3.2e38f

#define PRE_BLKS 32
#define KNN_BLKS (NBATCH * 64)   // 64 chunks of 32 points per batch
#define FUSED_LDS 54400

// ---- workspace layout (in floats) ----
#define WS_PRE 0                            // 16384*24
#define WS_AUX (16384 * 24)                 // 16384*72
#define WS_IDX (WS_AUX + 16384 * 72)        // 16384*16 ints

// Fused kernel: blocks [0,32) = fold+pre+aux, blocks [32,544) = exact 16-NN.
__global__ __launch_bounds__(512) void fused_kernel(
    const float* __restrict__ x,
    const float* __restrict__ w_pre, const float* __restrict__ b_pre,
    const float* __restrict__ g_pre, const float* __restrict__ be_pre,
    const float* __restrict__ m_pre, const float* __restrict__ v_pre,
    const float* __restrict__ w1, const float* __restrict__ g1,
    const float* __restrict__ be1, const float* __restrict__ m1,
    const float* __restrict__ v1,
    const float* __restrict__ w2, const float* __restrict__ g2,
    const float* __restrict__ be2, const float* __restrict__ m2,
    const float* __restrict__ v2, const float* __restrict__ w3,
    float* __restrict__ pre, float* __restrict__ aux,
    int* __restrict__ knn_out) {
  extern __shared__ char smem[];
  int tid = threadIdx.x;
  if (blockIdx.x < PRE_BLKS) {
    // ---- fold BN into weights (per-block, in LDS), then pre + aux ----
    float* fwp = (float*)smem;      // 72
    float* fbp = fwp + 72;          // 24
    float* fw1 = fbp + 24;          // 576
    float* fb1 = fw1 + 576;         // 12
    float* fw2 = fb1 + 12;          // 720
    float* fb2 = fw2 + 720;         // 12
    if (tid < 72) { int o = tid / 3; fwp[tid] = w_pre[tid] * (g_pre[o] / sqrtf(v_pre[o] + EPS)); }
    if (tid < 24) { float inv = g_pre[tid] / sqrtf(v_pre[tid] + EPS);
                    fbp[tid] = (b_pre[tid] - m_pre[tid]) * inv + be_pre[tid]; }
    for (int j = tid; j < 576; j += 512) { int o = j / 48; fw1[j] = w1[j] * (g1[o] / sqrtf(v1[o] + EPS)); }
    if (tid < 12) { float inv = g1[tid] / sqrtf(v1[tid] + EPS); fb1[tid] = be1[tid] - m1[tid] * inv; }
    for (int j = tid; j < 720; j += 512) { int o = j / 60; fw2[j] = w2[j] * (g2[o] / sqrtf(v2[o] + EPS)); }
    if (tid < 12) { float inv = g2[tid] / sqrtf(v2[tid] + EPS); fb2[tid] = be2[tid] - m2[tid] * inv; }
    __syncthreads();
    int p = blockIdx.x * 512 + tid;          // 0..16383
    int b = p >> 11, n = p & (NPTS - 1);
    const float* xb = x + (size_t)b * 3 * NPTS;
    float x0 = xb[n], x1 = xb[NPTS + n], x2 = xb[2 * NPTS + n];
    float pr[24];
#pragma unroll
    for (int c = 0; c < 24; ++c) {
      float v = fmaf(fwp[c * 3 + 0], x0,
                fmaf(fwp[c * 3 + 1], x1,
                fmaf(fwp[c * 3 + 2], x2, fbp[c])));
      pr[c] = fmaxf(v, 0.f);
    }
    float4* o4 = (float4*)(pre + (size_t)p * 24);
#pragma unroll
    for (int i = 0; i < 6; ++i)
      o4[i] = make_float4(pr[4*i], pr[4*i+1], pr[4*i+2], pr[4*i+3]);
    float* A = aux + (size_t)p * 72;
#pragma unroll
    for (int o = 0; o < 12; ++o) {
      float u1 = fb1[o], a1 = 0.f, u2 = fb2[o], a2 = 0.f, u3 = 0.f, a3 = 0.f;
#pragma unroll
      for (int i = 0; i < 24; ++i) {
        u1 = fmaf(fw1[o*48 + i],      pr[i], u1);
        a1 = fmaf(fw1[o*48 + 24 + i], pr[i], a1);
        u2 = fmaf(fw2[o*60 + 12 + i], pr[i], u2);
        a2 = fmaf(fw2[o*60 + 36 + i], pr[i], a2);
        u3 = fmaf(w3[o*72 + 24 + i],  pr[i], u3);
        a3 = fmaf(w3[o*72 + 48 + i],  pr[i], a3);
      }
      A[o] = u1; A[12+o] = u2; A[24+o] = u3;
      A[36+o] = a1; A[48+o] = a2; A[60+o] = a3;
    }
    return;
  }
  // ---- exact 16-NN: 32 points x 16 slices of 128 candidates ----
  float4* C4   = (float4*)smem;              // [2048] (2x,2y,2z,sq), 32 KB
  float* slist = (float*)(smem + 32768);     // [8 lists][16 vals][32 pts], 16 KB
  float* sd2   = (float*)(smem + 49152);     // [32][20]
  int*   sidx  = (int*)(smem + 51712);       // [32][20]
  int*   scnt  = (int*)(smem + 54272);       // [32]
  int bi = blockIdx.x - PRE_BLKS;
  int b = bi >> 6, chunk = bi & 63;
  const float* xb = x + (size_t)b * 3 * NPTS;
  for (int j = tid; j < NPTS; j += 512) {
    float xx = xb[j], yy = xb[NPTS + j], zz = xb[2 * NPTS + j];
    float sq = __fadd_rn(__fadd_rn(__fmul_rn(xx, xx), __fmul_rn(yy, yy)),
                         __fmul_rn(zz, zz));
    // store 2-scaled coords: x*(2xj) == 2*(x*xj) exactly (exponent shift)
    C4[j] = make_float4(2.0f * xx, 2.0f * yy, 2.0f * zz, sq);
  }
  for (int j = tid; j < 32 * 20; j += 512) sidx[j] = 0;
  if (tid < 32) scnt[tid] = 0;
  __syncthreads();
  int p = tid & 31, s = tid >> 5;            // point 0..31, slice 0..15
  int n = chunk * 32 + p;
  float4 me4 = C4[n];
  float mex = 0.5f * me4.x, mey = 0.5f * me4.y, mez = 0.5f * me4.z;
  float sqn = me4.w;
  const float4* Cs = C4 + s * 128;
  int selfc = n - s * 128;                   // in [0,128) only for self slice
  // Phase 1: branchless sorted-16 (values only)
  float L[16];
#pragma unroll
  for (int t = 0; t < 16; ++t) L[t] = BIG;
#pragma unroll 4
  for (int c = 0; c < 128; ++c) {
    float4 q = Cs[c];
    float dot2 = __fadd_rn(__fadd_rn(__fmul_rn(mex, q.x), __fmul_rn(mey, q.y)),
                           __fmul_rn(mez, q.z));
    float d2 = __fsub_rn(__fadd_rn(sqn, q.w), dot2);
    d2 = (c == selfc) ? BIG : d2;
#pragma unroll
    for (int t = 15; t >= 1; --t) L[t] = fminf(fmaxf(L[t-1], d2), L[t]);
    L[0] = fminf(L[0], d2);
  }
  // wave-level merge of slice pairs (s, s^1) via shfl: 16 lists -> 8
  {
    float bb[16], m16[16];
#pragma unroll
    for (int i = 0; i < 16; ++i) bb[i] = __shfl_xor(L[i], 32, 64);
#pragma unroll
    for (int i = 0; i < 16; ++i) m16[i] = fminf(L[i], bb[15 - i]);
#pragma unroll
    for (int d = 8; d >= 1; d >>= 1) {
#pragma unroll
      for (int i = 0; i < 16; ++i) {
        if (!(i & d)) {
          float lo = fminf(m16[i], m16[i | d]);
          float hi = fmaxf(m16[i], m16[i | d]);
          m16[i] = lo; m16[i | d] = hi;
        }
      }
    }
    if (!(s & 1)) {
#pragma unroll
      for (int i = 0; i < 16; ++i) slist[((s >> 1) * 16 + i) * 32 + p] = m16[i];
    }
  }
  __syncthreads();
  // Phase 2: merge tree 8 -> 4 -> 2 -> 1 lists (parallel over points)
  for (int W = 4; W >= 1; W >>= 1) {
    int w = tid >> 5;
    bool act = (w < W);
    float a[16], bb[16];
    if (act) {
#pragma unroll
      for (int i = 0; i < 16; ++i) a[i]  = slist[((2 * w) * 16 + i) * 32 + p];
#pragma unroll
      for (int i = 0; i < 16; ++i) bb[i] = slist[((2 * w + 1) * 16 + i) * 32 + p];
    }
    __syncthreads();
    if (act) {
      float m16[16];
#pragma unroll
      for (int i = 0; i < 16; ++i) m16[i] = fminf(a[i], bb[15 - i]);
#pragma unroll
      for (int d = 8; d >= 1; d >>= 1) {
#pragma unroll
        for (int i = 0; i < 16; ++i) {
          if (!(i & d)) {
            float lo = fminf(m16[i], m16[i | d]);
            float hi = fmaxf(m16[i], m16[i | d]);
            m16[i] = lo; m16[i | d] = hi;
          }
        }
      }
#pragma unroll
      for (int i = 0; i < 16; ++i) slist[(w * 16 + i) * 32 + p] = m16[i];
    }
    __syncthreads();
  }
  float tau = slist[15 * 32 + p];            // exact 16th smallest (self excluded)
  // Phase 3: rescan, collect indices with d2 <= tau
#pragma unroll 4
  for (int c = 0; c < 128; ++c) {
    float4 q = Cs[c];
    float dot2 = __fadd_rn(__fadd_rn(__fmul_rn(mex, q.x), __fmul_rn(mey, q.y)),
                           __fmul_rn(mez, q.z));
    float d2 = __fsub_rn(__fadd_rn(sqn, q.w), dot2);
    int j = s * 128 + c;
    if (d2 <= tau && j != n) {
      int pos = atomicAdd(&scnt[p], 1);
      if (pos < 20) { sd2[p * 20 + pos] = d2; sidx[p * 20 + pos] = j; }
    }
  }
  __syncthreads();
  // Phase 4: rare tie fixup — keep 16 smallest by (d2, idx) lexicographic
  if (tid < 32) {
    int c = scnt[tid]; if (c > 20) c = 20;
    if (c > 16) {
      for (int t = 0; t < 16; ++t) {
        int best = t;
        for (int u = t + 1; u < c; ++u) {
          float da = sd2[tid * 20 + u], db = sd2[tid * 20 + best];
          int ia = sidx[tid * 20 + u], ib = sidx[tid * 20 + best];
          if (da < db || (da == db && ia < ib)) best = u;
        }
        float td = sd2[tid * 20 + t]; sd2[tid * 20 + t] = sd2[tid * 20 + best]; sd2[tid * 20 + best] = td;
        int ti = sidx[tid * 20 + t]; sidx[tid * 20 + t] = sidx[tid * 20 + best]; sidx[tid * 20 + best] = ti;
      }
    }
  }
  __syncthreads();
  {
    int pp = tid >> 4, kk = tid & 15;        // 512 threads = 32 pts x 16 nbrs
    knn_out[((size_t)b * NPTS + chunk * 32 + pp) * KNB + kk] = sidx[pp * 20 + kk];
  }
}

// Fused edge-MLP + max. 16 lanes/point; neighbor-dependent 12x12 blocks only.
__global__ __launch_bounds__(256) void mlp_kernel(
    const float* __restrict__ pre, const float* __restrict__ aux,
    const int* __restrict__ knn, const float* __restrict__ x,
    const float* __restrict__ w2, const float* __restrict__ g2,
    const float* __restrict__ v2, const float* __restrict__ w3,
    float* __restrict__ out) {
  __shared__ float sW2h[144], sW3h2[144], sW3h1[144];
  __shared__ float sout[87 * 16];
  int tid = threadIdx.x;
  if (tid < 144) {
    int o = tid / 12, i = tid - o * 12;
    float inv2 = g2[o] / sqrtf(v2[o] + EPS);
    sW2h[tid]  = w2[o * 60 + i] * inv2;
    sW3h2[tid] = w3[o * 72 + i];
    sW3h1[tid] = w3[o * 72 + 12 + i];
  }
  __syncthreads();
  int k = tid & 15, pl = tid >> 4;
  int p = blockIdx.x * 16 + pl;            // 0..16383
  int b = p >> 11, n = p & (NPTS - 1);
  int nb = knn[(size_t)p * KNB + k];
  const float4* u4 = (const float4*)(aux + (size_t)p * 72);
  const float4* a4 = (const float4*)(aux + ((size_t)(b << 11) + nb) * 72 + 36);
  float uc[36], av[36];
#pragma unroll
  for (int i = 0; i < 9; ++i) {
    float4 t = u4[i];
    uc[4*i] = t.x; uc[4*i+1] = t.y; uc[4*i+2] = t.z; uc[4*i+3] = t.w;
    float4 t2 = a4[i];
    av[4*i] = t2.x; av[4*i+1] = t2.y; av[4*i+2] = t2.z; av[4*i+3] = t2.w;
  }
  float h1[12], h2[12], h3[12];
#pragma unroll
  for (int o = 0; o < 12; ++o) h1[o] = fmaxf(uc[o] + av[o], 0.f);
#pragma unroll
  for (int o = 0; o < 12; ++o) {
    float a = uc[12 + o] + av[12 + o];
#pragma unroll
    for (int i = 0; i < 12; ++i) a = fmaf(sW2h[o * 12 + i], h1[i], a);
    h2[o] = fmaxf(a, 0.f);
  }
#pragma unroll
  for (int o = 0; o < 12; ++o) {
    float a = uc[24 + o] + av[24 + o];
#pragma unroll
    for (int i = 0; i < 12; ++i) a = fmaf(sW3h2[o * 12 + i], h2[i], a);
#pragma unroll
    for (int i = 0; i < 12; ++i) a = fmaf(sW3h1[o * 12 + i], h1[i], a);
    h3[o] = a;
  }
  float nbf[24];
  const float4* pn4 = (const float4*)(pre + ((size_t)(b << 11) + nb) * 24);
#pragma unroll
  for (int i = 0; i < 6; ++i) {
    float4 t = pn4[i];
    nbf[4*i] = t.x; nbf[4*i+1] = t.y; nbf[4*i+2] = t.z; nbf[4*i+3] = t.w;
  }
#pragma unroll
  for (int m = 1; m < 16; m <<= 1) {
#pragma unroll
    for (int o = 0; o < 12; ++o) {
      h1[o] = fmaxf(h1[o], __shfl_xor(h1[o], m, 16));
      h2[o] = fmaxf(h2[o], __shfl_xor(h2[o], m, 16));
      h3[o] = fmaxf(h3[o], __shfl_xor(h3[o], m, 16));
    }
#pragma unroll
    for (int i = 0; i < 24; ++i)
      nbf[i] = fmaxf(nbf[i], __shfl_xor(nbf[i], m, 16));
  }
  if (k == 0) {
    const float4* c4 = (const float4*)(pre + (size_t)p * 24);
#pragma unroll
    for (int o = 0; o < 12; ++o) {
      sout[(0  + o) * 16 + pl] = h3[o];
      sout[(12 + o) * 16 + pl] = h2[o];
      sout[(24 + o) * 16 + pl] = h1[o];
    }
#pragma unroll
    for (int i = 0; i < 6; ++i) {
      float4 t = c4[i];
      sout[(36 + 4*i    ) * 16 + pl] = t.x;
      sout[(36 + 4*i + 1) * 16 + pl] = t.y;
      sout[(36 + 4*i + 2) * 16 + pl] = t.z;
      sout[(36 + 4*i + 3) * 16 + pl] = t.w;
    }
#pragma unroll
    for (int i = 0; i < 24; ++i) sout[(60 + i) * 16 + pl] = nbf[i];
    const float* xb = x + (size_t)b * 3 * NPTS + n;
    sout[84 * 16 + pl] = xb[0];
    sout[85 * 16 + pl] = xb[NPTS];
    sout[86 * 16 + pl] = xb[2 * NPTS];
  }
  __syncthreads();
  int n0 = (blockIdx.x * 16) & (NPTS - 1);
  float* ob = out + (size_t)b * 87 * NPTS;
  for (int j2 = tid; j2 < 87 * 16; j2 += 256) {
    int c = j2 >> 4, i = j2 & 15;
    ob[(size_t)c * NPTS + n0 + i] = sout[j2];
  }
}

extern "C" void kernel_launch(void* const* d_in, const int* in_sizes, int n_in,
                              void* d_out, int out_size, void* d_ws, size_t ws_size,
                              hipStream_t stream) {
  (void)in_sizes; (void)n_in; (void)out_size; (void)ws_size;
  const float* x     = (const float*)d_in[0];
  const float* w_pre = (const float*)d_in[1];
  const float* b_pre = (const float*)d_in[2];
  const float* g_pre = (const float*)d_in[3];
  const float* be_pre= (const float*)d_in[4];
  const float* m_pre = (const float*)d_in[5];
  const float* v_pre = (const float*)d_in[6];
  const float* w1    = (const float*)d_in[7];
  const float* g1    = (const float*)d_in[8];
  const float* be1   = (const float*)d_in[9];
  const float* m1    = (const float*)d_in[10];
  const float* v1    = (const float*)d_in[11];
  const float* w2    = (const float*)d_in[12];
  const float* g2    = (const float*)d_in[13];
  const float* be2   = (const float*)d_in[14];
  const float* m2    = (const float*)d_in[15];
  const float* v2    = (const float*)d_in[16];
  const float* w3    = (const float*)d_in[17];
  float* ws  = (float*)d_ws;
  float* pre = ws + WS_PRE;
  float* aux = ws + WS_AUX;
  int*   knn = (int*)(ws + WS_IDX);
  float* out = (float*)d_out;

  fused_kernel<<<PRE_BLKS + KNN_BLKS, 512, FUSED_LDS, stream>>>(
      x, w_pre, b_pre, g_pre, be_pre, m_pre, v_pre,
      w1, g1, be1, m1, v1, w2, g2, be2, m2, v2, w3,
      pre, aux, knn);
  mlp_kernel<<<NBATCH * NPTS / 16, 256, 0, stream>>>(pre, aux, knn, x,
                                                     w2, g2, v2, w3, out);
}